// Round 13
// baseline (1011.376 us; speedup 1.0000x reference)
//
#include <hip/hip_runtime.h>
#include <hip/hip_cooperative_groups.h>
namespace cg = cooperative_groups;

// ---- problem constants ----
constexpr int B_    = 64;
constexpr int NPG_  = 512;
constexpr int D_    = 128;
constexpr int K_    = 5;
constexpr int NHID_ = 50;
constexpr int CB_   = 512;
constexpr int N_    = B_ * NPG_;   // 32768
constexpr int E_    = N_ * 16;     // 524288
constexpr float BN_SCALE_ = 0.99999500003749969f;
constexpr float EPS_ = 1e-6f;

typedef __attribute__((ext_vector_type(8))) short bf16x8_t;
typedef __attribute__((ext_vector_type(4))) float f32x4_t;

__device__ __forceinline__ unsigned short f2bf(float x) {
    unsigned int u = __float_as_uint(x);
    unsigned int r = (u + 0x7FFFu + ((u >> 16) & 1u)) >> 16;   // RNE
    return (unsigned short)r;
}
__device__ __forceinline__ float bf2f(unsigned short b) {
    return __uint_as_float(((unsigned int)b) << 16);
}

__device__ __forceinline__ f32x4_t mfma3(bf16x8_t a0, bf16x8_t a1,
                                         bf16x8_t b0, bf16x8_t b1, f32x4_t acc) {
    acc = __builtin_amdgcn_mfma_f32_16x16x32_bf16(a1, b0, acc, 0, 0, 0);
    acc = __builtin_amdgcn_mfma_f32_16x16x32_bf16(a0, b1, acc, 0, 0, 0);
    acc = __builtin_amdgcn_mfma_f32_16x16x32_bf16(a0, b0, acc, 0, 0, 0);
    return acc;
}

// =================== cooperative build: prep + CSR (512 x 256) ===================
__global__ void k_build(const int* __restrict__ x, const float* __restrict__ emb,
                        float* __restrict__ h, int* __restrict__ counts,
                        const float* __restrict__ gw1, const float* __restrict__ gw2,
                        unsigned short* __restrict__ w1h, unsigned short* __restrict__ w1l,
                        unsigned short* __restrict__ w2h, unsigned short* __restrict__ w2l,
                        const int* __restrict__ src, const int* __restrict__ dst,
                        int* __restrict__ rowptr, int* __restrict__ woff,
                        int* __restrict__ col) {
    cg::grid_group grid = cg::this_grid();
    __shared__ int lsums[256];
    int bid = blockIdx.x, t = threadIdx.x;
    int gt = bid * 256 + t;                 // [0, 131072)

    // ---- P0: zero counts + weight split + embedding ----
    if (gt < N_) counts[gt] = 0;
    for (int e = gt; e < 196608; e += 131072) {
        int layer = e >> 16, rem = e & 65535;
        if (rem < 32768) {
            int k = rem >> 8, n = rem & 255;
            float v = gw1[layer * 32768 + rem];
            unsigned short h0 = f2bf(v);
            int o = layer * 32768 +
                    ((((n >> 4) * 4 + (k >> 5)) * 64 + ((k >> 3) & 3) * 16 + (n & 15)) << 3) + (k & 7);
            w1h[o] = h0; w1l[o] = f2bf(v - bf2f(h0));
        } else {
            int rr = rem - 32768;
            int c = rr >> 7, n = rr & 127;
            float v = gw2[layer * 32768 + rr];
            unsigned short h0 = f2bf(v);
            int o = layer * 32768 +
                    ((((n >> 4) * 8 + (c >> 5)) * 64 + ((c >> 3) & 3) * 16 + (n & 15)) << 3) + (c & 7);
            w2h[o] = h0; w2l[o] = f2bf(v - bf2f(h0));
        }
    }
    for (int i = gt; i < N_ * D_; i += 131072) {
        int node = i >> 7, f = i & 127;
        h[i] = emb[x[node] * D_ + f];
    }
    grid.sync();

    // ---- P1: count ----
    for (int e = gt; e < E_; e += 131072) atomicAdd(&counts[dst[e]], 1);
    grid.sync();

    // ---- P2: exclusive scan (block 0, 256 threads x 128 elems) ----
    if (bid == 0) {
        int base = t * 128;
        int s = 0;
        for (int i = 0; i < 128; i++) s += counts[base + i];
        lsums[t] = s;
        __syncthreads();
        for (int off = 1; off < 256; off <<= 1) {
            int v = lsums[t];
            int add = (t >= off) ? lsums[t - off] : 0;
            __syncthreads();
            lsums[t] = v + add;
            __syncthreads();
        }
        int excl = lsums[t] - s;
        for (int i = 0; i < 128; i++) {
            int c = counts[base + i];
            rowptr[base + i] = excl;
            woff[base + i]   = excl;
            excl += c;
        }
        if (t == 255) rowptr[N_] = excl;
    }
    grid.sync();

    // ---- P3: fill ----
    for (int e = gt; e < E_; e += 131072) {
        int d = dst[e];
        int p = atomicAdd(&woff[d], 1);
        col[p] = src[e];
    }
}

// =================== fused GIN layer (r10 — verified, unchanged) ===================
constexpr int LDH = 264;
constexpr int COLCAP = 1024;
__global__ __launch_bounds__(512) void k_gin(
    const float* __restrict__ hIn, const int* __restrict__ rowptr,
    const int* __restrict__ col,
    const unsigned short* __restrict__ w1h, const unsigned short* __restrict__ w1l,
    const unsigned short* __restrict__ w2h, const unsigned short* __restrict__ w2l,
    const float* __restrict__ b1, const float* __restrict__ b2,
    const float* __restrict__ gamma, const float* __restrict__ beta,
    int relu_out, float* __restrict__ hOut) {
    __shared__ int colS[COLCAP];
    __shared__ unsigned short bufH[32 * LDH];
    __shared__ unsigned short bufL[32 * LDH];
    int i = blockIdx.x;
    int xcd = i & 7;
    int slot = i >> 3;
    int g = (slot >> 4) * 8 + xcd;
    int tile = slot & 15;
    int rowBase = g * 512 + tile * 32;
    int t = threadIdx.x;
    int w = t >> 6, l = t & 63;
    int l15 = l & 15, quad = l >> 4;

    int ebase = rowptr[rowBase];
    int ecnt  = rowptr[rowBase + 32] - ebase;
    bool inLds = (ecnt <= COLCAP);
    if (inLds)
        for (int j = t; j < ecnt; j += 512) colS[j] = col[ebase + j];
    __syncthreads();

    #pragma unroll
    for (int jj = 0; jj < 4; jj++) {
        int row = w * 4 + jj;
        int node = rowBase + row;
        int beg = rowptr[node], end = rowptr[node + 1];
        float a0 = hIn[(size_t)node * D_ + l];
        float a1 = hIn[(size_t)node * D_ + l + 64];
        int e = beg;
        for (; e + 8 <= end; e += 8) {
            int c[8];
            #pragma unroll
            for (int u = 0; u < 8; u++)
                c[u] = inLds ? colS[e - ebase + u] : col[e + u];
            float p[8], q[8];
            #pragma unroll
            for (int u = 0; u < 8; u++) {
                p[u] = hIn[(size_t)c[u] * D_ + l];
                q[u] = hIn[(size_t)c[u] * D_ + l + 64];
            }
            #pragma unroll
            for (int u = 0; u < 8; u++) { a0 += p[u]; a1 += q[u]; }
        }
        for (; e < end; e++) {
            int c = inLds ? colS[e - ebase] : col[e];
            a0 += hIn[(size_t)c * D_ + l];
            a1 += hIn[(size_t)c * D_ + l + 64];
        }
        unsigned short h0 = f2bf(a0);
        bufH[row * LDH + l] = h0;
        bufL[row * LDH + l] = f2bf(a0 - bf2f(h0));
        unsigned short h1 = f2bf(a1);
        bufH[row * LDH + l + 64] = h1;
        bufL[row * LDH + l + 64] = f2bf(a1 - bf2f(h1));
    }
    __syncthreads();

    f32x4_t acc[2][2];
    #pragma unroll
    for (int nt = 0; nt < 2; nt++) {
        float bb = b1[w * 32 + nt * 16 + l15];
        acc[0][nt] = (f32x4_t){bb, bb, bb, bb};
        acc[1][nt] = (f32x4_t){bb, bb, bb, bb};
    }
    #pragma unroll
    for (int kk = 0; kk < 4; kk++) {
        bf16x8_t ah[2], al[2];
        #pragma unroll
        for (int mt = 0; mt < 2; mt++) {
            int addr = (mt * 16 + l15) * LDH + kk * 32 + quad * 8;
            ah[mt] = *(const bf16x8_t*)&bufH[addr];
            al[mt] = *(const bf16x8_t*)&bufL[addr];
        }
        #pragma unroll
        for (int nt = 0; nt < 2; nt++) {
            int n16 = w * 2 + nt;
            int ga = (((n16 * 4 + kk) * 64 + l) << 3);
            bf16x8_t bh = *(const bf16x8_t*)&w1h[ga];
            bf16x8_t bl = *(const bf16x8_t*)&w1l[ga];
            acc[0][nt] = mfma3(ah[0], al[0], bh, bl, acc[0][nt]);
            acc[1][nt] = mfma3(ah[1], al[1], bh, bl, acc[1][nt]);
        }
    }
    __syncthreads();

    #pragma unroll
    for (int mt = 0; mt < 2; mt++)
        #pragma unroll
        for (int nt = 0; nt < 2; nt++) {
            int colL = w * 32 + nt * 16 + l15;
            #pragma unroll
            for (int r = 0; r < 4; r++) {
                int row = mt * 16 + quad * 4 + r;
                float v = fmaxf(acc[mt][nt][r], 0.f);
                unsigned short h0 = f2bf(v);
                bufH[row * LDH + colL] = h0;
                bufL[row * LDH + colL] = f2bf(v - bf2f(h0));
            }
        }
    __syncthreads();

    f32x4_t acc2[2];
    {
        float bb = b2[w * 16 + l15];
        acc2[0] = (f32x4_t){bb, bb, bb, bb};
        acc2[1] = (f32x4_t){bb, bb, bb, bb};
    }
    #pragma unroll
    for (int kkG = 0; kkG < 8; kkG++) {
        bf16x8_t ah[2], al[2];
        #pragma unroll
        for (int mt = 0; mt < 2; mt++) {
            int addr = (mt * 16 + l15) * LDH + kkG * 32 + quad * 8;
            ah[mt] = *(const bf16x8_t*)&bufH[addr];
            al[mt] = *(const bf16x8_t*)&bufL[addr];
        }
        int ga = (((w * 8 + kkG) * 64 + l) << 3);
        bf16x8_t bh = *(const bf16x8_t*)&w2h[ga];
        bf16x8_t bl = *(const bf16x8_t*)&w2l[ga];
        acc2[0] = mfma3(ah[0], al[0], bh, bl, acc2[0]);
        acc2[1] = mfma3(ah[1], al[1], bh, bl, acc2[1]);
    }
    {
        int colC = w * 16 + l15;
        float gm = BN_SCALE_ * gamma[colC];
        float be = beta[colC];
        #pragma unroll
        for (int mt = 0; mt < 2; mt++)
            #pragma unroll
            for (int r = 0; r < 4; r++) {
                int row = mt * 16 + quad * 4 + r;
                float v = fmaf(acc2[mt][r], gm, be);
                if (relu_out) v = fmaxf(v, 0.f);
                hOut[(size_t)(rowBase + row) * 128 + colC] = v;
            }
    }
}

// =================== atomic split-K GEMM tile (shared by mega phases) ===================
__device__ __forceinline__ void gemm_tile_atomic(
    const float* __restrict__ A, int lda, int kc,
    const float* __restrict__ W, int ldw,
    float* __restrict__ C, int ldc, int coff, int actA,
    float* aT, float* wT) {
    int t = threadIdx.x;
    for (int i = t; i < 1024; i += 256) {
        int r = i >> 4, c4 = (i & 15) << 2;
        float4 av = *(const float4*)&A[(size_t)r * lda + kc + c4];
        if (actA) {
            av.x = fmaxf(av.x, 0.f); av.y = fmaxf(av.y, 0.f);
            av.z = fmaxf(av.z, 0.f); av.w = fmaxf(av.w, 0.f);
        }
        *(float4*)&aT[r * 68 + c4] = av;
        *(float4*)&wT[r * 68 + c4] = *(const float4*)&W[(size_t)(kc + r) * ldw + coff + c4];
    }
    __syncthreads();
    int tx = t & 15, ty = t >> 4;
    float acc[4][4] = {};
    #pragma unroll 4
    for (int k = 0; k < 64; k += 4) {
        float w[4][4];
        #pragma unroll
        for (int kk = 0; kk < 4; kk++)
            #pragma unroll
            for (int j = 0; j < 4; j++)
                w[kk][j] = wT[(k + kk) * 68 + tx + j * 16];
        #pragma unroll
        for (int r = 0; r < 4; r++) {
            float4 av = *(const float4*)&aT[(ty * 4 + r) * 68 + k];
            #pragma unroll
            for (int j = 0; j < 4; j++) {
                acc[r][j] = fmaf(av.x, w[0][j], acc[r][j]);
                acc[r][j] = fmaf(av.y, w[1][j], acc[r][j]);
                acc[r][j] = fmaf(av.z, w[2][j], acc[r][j]);
                acc[r][j] = fmaf(av.w, w[3][j], acc[r][j]);
            }
        }
    }
    #pragma unroll
    for (int r = 0; r < 4; r++)
        #pragma unroll
        for (int j = 0; j < 4; j++)
            atomicAdd(&C[(size_t)(ty * 4 + r) * ldc + coff + tx + j * 16], acc[r][j]);
}

// =================== cooperative tail megakernel (512 x 256) ===================
__global__ void k_mega(
    const float* __restrict__ h,
    const float* __restrict__ pW1, const float* __restrict__ pb1,
    const float* __restrict__ pW2, const float* __restrict__ pb2,
    float* __restrict__ pacc, float* __restrict__ pss, float* __restrict__ prs,
    const float* __restrict__ cb,
    float* __restrict__ residue, float* __restrict__ catbuf, float* __restrict__ zq,
    float* __restrict__ qbuf, float* __restrict__ kbuf, float* __restrict__ vbuf,
    float* __restrict__ attbuf, float* __restrict__ g1h, float* __restrict__ fusedbuf,
    float* __restrict__ z1, float* __restrict__ z2,
    const float* __restrict__ Wq, const float* __restrict__ Wk,
    const float* __restrict__ Wv, const float* __restrict__ Wo,
    const float* __restrict__ gW1, const float* __restrict__ gb1,
    const float* __restrict__ gW2, const float* __restrict__ gb2,
    const float* __restrict__ cW1, const float* __restrict__ cb1,
    const float* __restrict__ cW2, const float* __restrict__ cb2,
    const float* __restrict__ cW3, const float* __restrict__ cb3,
    float* __restrict__ out) {
    cg::grid_group grid = cg::this_grid();
    __shared__ __align__(16) char smemRaw[50480];
    int bid = blockIdx.x, t = threadIdx.x;
    int gt = bid * 256 + t;

    // ======== P0: partitioner + cf1 (512 tasks) + tinit ========
    {
        float* zt    = (float*)smemRaw;     // 8192
        float* ht    = zt + 8192;           // 3328
        float* lt    = ht + 3328;           // 320
        float* redp  = lt + 320;            // 768
        float* ssred = redp + 768;          // 10
        int blk = bid;
        int base = blk * 64;
        #pragma unroll
        for (int i = 0; i < 32; i++) { int idx = t + i * 256; zt[idx] = h[(size_t)base * D_ + idx]; }
        __syncthreads();
        int tx = t & 63, ty = t >> 6, r0 = ty * 16;
        if (tx < NHID_) {
            float acc[16];
            float bb = pb1[tx];
            #pragma unroll
            for (int r = 0; r < 16; r++) acc[r] = bb;
            for (int k = 0; k < 128; k++) {
                float w = pW1[k * NHID_ + tx];
                #pragma unroll
                for (int r = 0; r < 16; r++) acc[r] = fmaf(zt[(r0 + r) * 128 + k], w, acc[r]);
            }
            #pragma unroll
            for (int r = 0; r < 16; r++) ht[(r0 + r) * 52 + tx] = fmaxf(acc[r], 0.f);
        }
        __syncthreads();
        if (tx < K_) {
            float acc[16];
            float bb = pb2[tx];
            #pragma unroll
            for (int r = 0; r < 16; r++) acc[r] = bb;
            for (int c = 0; c < NHID_; c++) {
                float w = pW2[c * K_ + tx];
                #pragma unroll
                for (int r = 0; r < 16; r++) acc[r] = fmaf(ht[(r0 + r) * 52 + c], w, acc[r]);
            }
            #pragma unroll
            for (int r = 0; r < 16; r++) lt[(r0 + r) * 5 + tx] = acc[r];
        }
        __syncthreads();
        if (t < 64) {
            float l0 = lt[t*5], l1 = lt[t*5+1], l2 = lt[t*5+2], l3 = lt[t*5+3], l4 = lt[t*5+4];
            float m = fmaxf(fmaxf(fmaxf(l0, l1), fmaxf(l2, l3)), l4);
            float e0 = expf(l0 - m), e1 = expf(l1 - m), e2 = expf(l2 - m),
                  e3 = expf(l3 - m), e4 = expf(l4 - m);
            float inv = 1.0f / (e0 + e1 + e2 + e3 + e4);
            lt[t*5]   = e0*inv; lt[t*5+1] = e1*inv; lt[t*5+2] = e2*inv;
            lt[t*5+3] = e3*inv; lt[t*5+4] = e4*inv;
        }
        __syncthreads();
        int d = t & 127, grp = t >> 7;
        float acc[5] = {0,0,0,0,0}, ssum[5] = {0,0,0,0,0}, rs = 0;
        #pragma unroll 4
        for (int i = 0; i < 32; i++) {
            int nl = grp * 32 + i;
            float hv = zt[nl * 128 + d];
            rs += hv;
            #pragma unroll
            for (int k = 0; k < 5; k++) {
                float sv = lt[nl * 5 + k];
                acc[k] = fmaf(sv, hv, acc[k]);
                ssum[k] += sv;
            }
        }
        if (grp == 1) {
            #pragma unroll
            for (int k = 0; k < 5; k++) redp[d * 6 + k] = acc[k];
            redp[d * 6 + 5] = rs;
        }
        if (d == 0) {
            #pragma unroll
            for (int k = 0; k < 5; k++) ssred[grp * 5 + k] = ssum[k];
        }
        __syncthreads();
        if (grp == 0) {
            #pragma unroll
            for (int k = 0; k < 5; k++) {
                acc[k] += redp[d * 6 + k];
                pacc[((size_t)blk * 5 + k) * 128 + d] = acc[k];
            }
            rs += redp[d * 6 + 5];
            prs[blk * 128 + d] = rs;
            if (d < 5) pss[blk * 5 + d] = ssred[d] + ssred[5 + d];
        }
        // tinit (atomic-GEMM target init), strided across whole grid
        for (int i = gt; i < 151552; i += 131072) {
            if (i < 8192) qbuf[i] = 0.f;
            else if (i < 49152) kbuf[i - 8192] = 0.f;
            else if (i < 90112) vbuf[i - 49152] = 0.f;
            else if (i < 98304) { int j = i - 90112; catbuf[(j >> 7) * 256 + 128 + (j & 127)] = 0.f; }
            else if (i < 102400) { int j = i - 98304; g1h[j] = gb1[j & 63]; }
            else if (i < 135168) { int j = i - 102400; z1[j] = cb1[j & 511]; }
            else { int j = i - 135168; z2[j] = cb2[j & 255]; }
        }
    }
    grid.sync();

    // ======== P1: cf2 + VQ (320 tasks) ========
    if (bid < 320) {
        float* row = (float*)smemRaw;       // 128
        float* bd  = row + 128;             // 256
        int*   bi  = (int*)(bd + 256);      // 256
        int g = bid / 5, k = bid - g * 5;
        if (t < 128) {
            float acc = 0, ss = 0;
            for (int ch = 0; ch < 8; ch++) {
                int blk = g * 8 + ch;
                acc += pacc[((size_t)blk * 5 + k) * 128 + t];
                ss  += pss[blk * 5 + k];
            }
            row[t] = acc / (ss + EPS_);
            if (k == 0) {
                float rs = 0;
                for (int ch = 0; ch < 8; ch++) rs += prs[(g * 8 + ch) * 128 + t];
                float rm = rs * (1.0f / 512.0f);
                residue[g * 128 + t] = rm;
                catbuf[g * 256 + t]  = rm;
            }
        }
        __syncthreads();
        float best = 1e30f; int bidx = 0;
        const float4* r4p = (const float4*)row;
        for (int j = t; j < CB_; j += 256) {
            const float4* cbr = (const float4*)(cb + j * 128);
            float d2 = 0;
            #pragma unroll 8
            for (int q = 0; q < 32; q++) {
                float4 c4 = cbr[q], r4 = r4p[q];
                float dx = r4.x - c4.x, dy = r4.y - c4.y;
                float dz = r4.z - c4.z, dw = r4.w - c4.w;
                d2 = fmaf(dx, dx, d2); d2 = fmaf(dy, dy, d2);
                d2 = fmaf(dz, dz, d2); d2 = fmaf(dw, dw, d2);
            }
            if (d2 < best || (d2 == best && j < bidx)) { best = d2; bidx = j; }
        }
        bd[t] = best; bi[t] = bidx;
        __syncthreads();
        for (int s = 128; s > 0; s >>= 1) {
            if (t < s) {
                if (bd[t + s] < bd[t] || (bd[t + s] == bd[t] && bi[t + s] < bi[t])) {
                    bd[t] = bd[t + s]; bi[t] = bi[t + s];
                }
            }
            __syncthreads();
        }
        int idx = bi[0];
        if (t < 128) zq[bid * 128 + t] = cb[idx * 128 + t];
    }
    grid.sync();

    // ======== P2: qkv (44 tasks) ========
    if (bid < 44) {
        float* aT = (float*)smemRaw;
        float* wT = aT + 64 * 68;
        int xb = bid & 1, yb = (bid >> 1) & 1, z = bid >> 2;
        const float* A; const float* W; float* C;
        if (z == 0)      { A = residue;                 W = Wq; C = qbuf; }
        else if (z < 6)  { A = zq + (z - 1) * 64 * 128; W = Wk; C = kbuf + (z - 1) * 64 * 128; }
        else             { A = zq + (z - 6) * 64 * 128; W = Wv; C = vbuf + (z - 6) * 64 * 128; }
        gemm_tile_atomic(A, 128, yb * 64, W, 128, C, 128, xb * 64, 0, aT, wT);
    }
    grid.sync();

    // ======== P3: attention (64 tasks) ========
    if (bid < 64) {
        float* q   = (float*)smemRaw;    // 128
        float* kk5 = q + 128;            // 640
        float* vv5 = kk5 + 640;          // 640
        float* aw  = vv5 + 640;          // 20
        int b = bid;
        if (t < 128) {
            q[t] = qbuf[b * 128 + t];
            #pragma unroll
            for (int j = 0; j < 5; j++) {
                kk5[j * 128 + t] = kbuf[(b * 5 + j) * 128 + t];
                vv5[j * 128 + t] = vbuf[(b * 5 + j) * 128 + t];
            }
        }
        __syncthreads();
        if (t < 20) {
            int hh = t / 5, j = t % 5;
            float s = 0;
            #pragma unroll
            for (int d = 0; d < 32; d++) s = fmaf(q[hh * 32 + d], kk5[j * 128 + hh * 32 + d], s);
            aw[t] = s * 0.17677669529663687f;
        }
        __syncthreads();
        if (t < 4) {
            float m = -1e30f;
            for (int j = 0; j < 5; j++) m = fmaxf(m, aw[t * 5 + j]);
            float e[5], sum = 0;
            for (int j = 0; j < 5; j++) { e[j] = expf(aw[t * 5 + j] - m); sum += e[j]; }
            for (int j = 0; j < 5; j++) aw[t * 5 + j] = e[j] / sum;
        }
        __syncthreads();
        if (t < 128) {
            int hh = t >> 5;
            float a = 0;
            #pragma unroll
            for (int j = 0; j < 5; j++) a = fmaf(aw[hh * 5 + j], vv5[j * 128 + t], a);
            attbuf[b * 128 + t] = a;
        }
    }
    grid.sync();

    // ======== P4: attO (4 tasks) ========
    if (bid < 4) {
        float* aT = (float*)smemRaw;
        float* wT = aT + 64 * 68;
        gemm_tile_atomic(attbuf, 128, (bid >> 1) * 64, Wo, 128,
                         catbuf + 128, 256, (bid & 1) * 64, 0, aT, wT);
    }
    grid.sync();

    // ======== P5: gate1 (4 tasks) ========
    if (bid < 4) {
        float* aT = (float*)smemRaw;
        float* wT = aT + 64 * 68;
        gemm_tile_atomic(catbuf, 256, bid * 64, gW1, 64, g1h, 64, 0, 0, aT, wT);
    }
    grid.sync();

    // ======== P6: gate2 + sigmoid + fuse (2 tasks) ========
    if (bid < 2) {
        float* aT = (float*)smemRaw;
        float* wT = aT + 64 * 68;
        int coff = bid * 64;
        for (int i = t; i < 1024; i += 256) {
            int r = i >> 4, c4 = (i & 15) << 2;
            float4 av = *(const float4*)&g1h[r * 64 + c4];
            av.x = fmaxf(av.x, 0.f); av.y = fmaxf(av.y, 0.f);
            av.z = fmaxf(av.z, 0.f); av.w = fmaxf(av.w, 0.f);
            *(float4*)&aT[r * 68 + c4] = av;
            *(float4*)&wT[r * 68 + c4] = *(const float4*)&gW2[r * 128 + coff + c4];
        }
        __syncthreads();
        int tx = t & 15, ty = t >> 4;
        float acc[4][4] = {};
        #pragma unroll 4
        for (int k = 0; k < 64; k += 4) {
            float w[4][4];
            #pragma unroll
            for (int kk = 0; kk < 4; kk++)
                #pragma unroll
                for (int j = 0; j < 4; j++)
                    w[kk][j] = wT[(k + kk) * 68 + tx + j * 16];
            #pragma unroll
            for (int r = 0; r < 4; r++) {
                float4 av = *(const float4*)&aT[(ty * 4 + r) * 68 + k];
                #pragma unroll
                for (int j = 0; j < 4; j++) {
                    acc[r][j] = fmaf(av.x, w[0][j], acc[r][j]);
                    acc[r][j] = fmaf(av.y, w[1][j], acc[r][j]);
                    acc[r][j] = fmaf(av.z, w[2][j], acc[r][j]);
                    acc[r][j] = fmaf(av.w, w[3][j], acc[r][j]);
                }
            }
        }
        #pragma unroll
        for (int r = 0; r < 4; r++)
            #pragma unroll
            for (int j = 0; j < 4; j++) {
                int col = coff + tx + j * 16;
                int row = ty * 4 + r;
                float gv = 1.f / (1.f + expf(-(acc[r][j] + gb2[col])));
                float rv = residue[row * 128 + col];
                float av = catbuf[row * 256 + 128 + col];
                fusedbuf[row * 128 + col] = gv * rv + (1.f - gv) * av;
            }
    }
    grid.sync();

    // ======== P7: cls1 (16 tasks) ========
    if (bid < 16) {
        float* aT = (float*)smemRaw;
        float* wT = aT + 64 * 68;
        gemm_tile_atomic(fusedbuf, 128, (bid >> 3) * 64, cW1, 512,
                         z1, 512, (bid & 7) * 64, 0, aT, wT);
    }
    grid.sync();

    // ======== P8: cls2 (32 tasks, relu on z1 read) ========
    if (bid < 32) {
        float* aT = (float*)smemRaw;
        float* wT = aT + 64 * 68;
        gemm_tile_atomic(z1, 512, (bid >> 2) * 64, cW2, 256,
                         z2, 256, (bid & 3) * 64, 1, aT, wT);
    }
    grid.sync();

    // ======== P9: cls3 (64 tasks, relu on z2 read) ========
    if (bid < 64) {
        float* red8 = (float*)smemRaw;
        int row = bid;
        float zv = fmaxf(z2[row * 256 + t], 0.f);
        float a0 = zv * cW3[t * 2];
        float a1 = zv * cW3[t * 2 + 1];
        #pragma unroll
        for (int off = 32; off > 0; off >>= 1) {
            a0 += __shfl_down(a0, off, 64);
            a1 += __shfl_down(a1, off, 64);
        }
        int wv = t >> 6;
        if ((t & 63) == 0) { red8[wv * 2] = a0; red8[wv * 2 + 1] = a1; }
        __syncthreads();
        if (t < 2) {
            float s = cb3[t] + red8[t] + red8[2 + t] + red8[4 + t] + red8[6 + t];
            out[row * 2 + t] = s;
        }
    }
}

// =================== launch ===================
extern "C" void kernel_launch(void* const* d_in, const int* in_sizes, int n_in,
                              void* d_out, int out_size, void* d_ws, size_t ws_size,
                              hipStream_t stream) {
    const int*   x          = (const int*)d_in[0];
    const int*   edge_index = (const int*)d_in[1];
    const float* emb      = (const float*)d_in[3];
    const float* gin_W1   = (const float*)d_in[4];
    const float* gin_b1   = (const float*)d_in[5];
    const float* gin_W2   = (const float*)d_in[6];
    const float* gin_b2   = (const float*)d_in[7];
    const float* bn_gamma = (const float*)d_in[8];
    const float* bn_beta  = (const float*)d_in[9];
    const float* part_W1  = (const float*)d_in[10];
    const float* part_b1  = (const float*)d_in[11];
    const float* part_W2  = (const float*)d_in[12];
    const float* part_b2  = (const float*)d_in[13];
    const float* Wq       = (const float*)d_in[14];
    const float* Wk       = (const float*)d_in[15];
    const float* Wv       = (const float*)d_in[16];
    const float* Wo       = (const float*)d_in[17];
    const float* gate_W1  = (const float*)d_in[18];
    const float* gate_b1  = (const float*)d_in[19];
    const float* gate_W2  = (const float*)d_in[20];
    const float* gate_b2  = (const float*)d_in[21];
    const float* codebook = (const float*)d_in[22];
    const float* cls_W1   = (const float*)d_in[23];
    const float* cls_b1   = (const float*)d_in[24];
    const float* cls_W2   = (const float*)d_in[25];
    const float* cls_b2   = (const float*)d_in[26];
    const float* cls_W3   = (const float*)d_in[27];
    const float* cls_b3   = (const float*)d_in[28];

    const int* srcp = edge_index;
    const int* dstp = edge_index + E_;

    // ---- workspace carve ----
    char* w = (char*)d_ws;
    float* hA = (float*)w;  w += (size_t)N_ * D_ * 4;
    float* hB = (float*)w;  w += (size_t)N_ * D_ * 4;
    int* counts = (int*)w;  w += (size_t)N_ * 4;
    int* rowptr = (int*)w;  w += (size_t)(N_ + 4) * 4;
    int* woff   = (int*)w;  w += (size_t)N_ * 4;
    int* col    = (int*)w;  w += (size_t)E_ * 4;
    unsigned short* w1h = (unsigned short*)w;  w += (size_t)3 * 32768 * 2;
    unsigned short* w1l = (unsigned short*)w;  w += (size_t)3 * 32768 * 2;
    unsigned short* w2h = (unsigned short*)w;  w += (size_t)3 * 32768 * 2;
    unsigned short* w2l = (unsigned short*)w;  w += (size_t)3 * 32768 * 2;

    // tail buffers live inside hA (dead after GIN L2 reads it)
    char* tz = (char*)hA;
    float* pacc     = (float*)tz;  tz += (size_t)512 * 5 * 128 * 4;
    float* pss      = (float*)tz;  tz += (size_t)512 * 5 * 4;
    float* prs      = (float*)tz;  tz += (size_t)512 * 128 * 4;
    float* zqb      = (float*)tz;  tz += (size_t)B_ * 5 * D_ * 4;
    float* residue  = (float*)tz;  tz += (size_t)B_ * D_ * 4;
    float* catbuf   = (float*)tz;  tz += (size_t)B_ * 2 * D_ * 4;
    float* qbuf     = (float*)tz;  tz += (size_t)B_ * D_ * 4;
    float* kbuf     = (float*)tz;  tz += (size_t)B_ * 5 * D_ * 4;
    float* vbuf     = (float*)tz;  tz += (size_t)B_ * 5 * D_ * 4;
    float* attbuf   = (float*)tz;  tz += (size_t)B_ * D_ * 4;
    float* g1h      = (float*)tz;  tz += (size_t)B_ * 64 * 4;
    float* fusedbuf = (float*)tz;  tz += (size_t)B_ * D_ * 4;
    float* z1       = (float*)tz;  tz += (size_t)B_ * 512 * 4;
    float* z2       = (float*)tz;  tz += (size_t)B_ * 256 * 4;

    // ---- cooperative build: prep + CSR ----
    {
        void* args[] = {(void*)&x, (void*)&emb, (void*)&hA, (void*)&counts,
                        (void*)&gin_W1, (void*)&gin_W2,
                        (void*)&w1h, (void*)&w1l, (void*)&w2h, (void*)&w2l,
                        (void*)&srcp, (void*)&dstp,
                        (void*)&rowptr, (void*)&woff, (void*)&col};
        hipLaunchCooperativeKernel((const void*)k_build, dim3(512), dim3(256),
                                   args, 0, stream);
    }

    // ---- GIN layers (ping-pong hA/hB; final in hB) ----
    const float* hin[3] = {hA, hB, hA};
    float*       hout[3] = {hB, hA, hB};
    for (int l = 0; l < 3; l++) {
        k_gin<<<1024, 512, 0, stream>>>(
            hin[l], rowptr, col,
            w1h + (size_t)l * 32768, w1l + (size_t)l * 32768,
            w2h + (size_t)l * 32768, w2l + (size_t)l * 32768,
            gin_b1 + (size_t)l * 256, gin_b2 + (size_t)l * 128,
            bn_gamma + (size_t)l * 128, bn_beta + (size_t)l * 128,
            (l < 2) ? 1 : 0, hout[l]);
    }

    // ---- cooperative tail megakernel ----
    {
        float* outp = (float*)d_out;
        void* args[] = {(void*)&hB,
                        (void*)&part_W1, (void*)&part_b1, (void*)&part_W2, (void*)&part_b2,
                        (void*)&pacc, (void*)&pss, (void*)&prs,
                        (void*)&codebook,
                        (void*)&residue, (void*)&catbuf, (void*)&zqb,
                        (void*)&qbuf, (void*)&kbuf, (void*)&vbuf,
                        (void*)&attbuf, (void*)&g1h, (void*)&fusedbuf,
                        (void*)&z1, (void*)&z2,
                        (void*)&Wq, (void*)&Wk, (void*)&Wv, (void*)&Wo,
                        (void*)&gate_W1, (void*)&gate_b1, (void*)&gate_W2, (void*)&gate_b2,
                        (void*)&cls_W1, (void*)&cls_b1, (void*)&cls_W2, (void*)&cls_b2,
                        (void*)&cls_W3, (void*)&cls_b3,
                        (void*)&outp};
        hipLaunchCooperativeKernel((const void*)k_mega, dim3(512), dim3(256),
                                   args, 0, stream);
    }
}

// Round 14
// 362.865 us; speedup vs baseline: 2.7872x; 2.7872x over previous
//
#include <hip/hip_runtime.h>

// ---- problem constants ----
constexpr int B_    = 64;
constexpr int NPG_  = 512;
constexpr int D_    = 128;
constexpr int K_    = 5;
constexpr int NHID_ = 50;
constexpr int CB_   = 512;
constexpr int N_    = B_ * NPG_;   // 32768
constexpr int E_    = N_ * 16;     // 524288
constexpr float BN_SCALE_ = 0.99999500003749969f;  // 1/sqrt(1+1e-5)
constexpr float EPS_ = 1e-6f;

typedef __attribute__((ext_vector_type(8))) short bf16x8_t;
typedef __attribute__((ext_vector_type(4))) float f32x4_t;

__device__ __forceinline__ unsigned short f2bf(float x) {
    unsigned int u = __float_as_uint(x);
    unsigned int r = (u + 0x7FFFu + ((u >> 16) & 1u)) >> 16;   // RNE
    return (unsigned short)r;
}
__device__ __forceinline__ float bf2f(unsigned short b) {
    return __uint_as_float(((unsigned int)b) << 16);
}

// 2-term split product-sum: (a0+a1)(b0+b1) ~= a1*b0 + a0*b1 + a0*b0 (error ~2^-16)
__device__ __forceinline__ f32x4_t mfma3(bf16x8_t a0, bf16x8_t a1,
                                         bf16x8_t b0, bf16x8_t b1, f32x4_t acc) {
    acc = __builtin_amdgcn_mfma_f32_16x16x32_bf16(a1, b0, acc, 0, 0, 0);
    acc = __builtin_amdgcn_mfma_f32_16x16x32_bf16(a0, b1, acc, 0, 0, 0);
    acc = __builtin_amdgcn_mfma_f32_16x16x32_bf16(a0, b0, acc, 0, 0, 0);
    return acc;
}

// =================== fused prep: zero counts + embedding + weight split ===================
// Weights stored in MFMA-fragment order (lane-contiguous 1 KB chunks).
__global__ void k_prep(const int* __restrict__ x, const float* __restrict__ emb,
                       float* __restrict__ h, int* __restrict__ counts,
                       const float* __restrict__ gw1, const float* __restrict__ gw2,
                       unsigned short* __restrict__ w1h, unsigned short* __restrict__ w1l,
                       unsigned short* __restrict__ w2h, unsigned short* __restrict__ w2l) {
    int b = blockIdx.x, t = threadIdx.x;
    if (b < 128) {
        counts[b * 256 + t] = 0;
        return;
    }
    if (b < 16512) {
        int i = (b - 128) * 256 + t;
        int node = i >> 7, f = i & 127;
        h[i] = emb[x[node] * D_ + f];
        return;
    }
    int e = (b - 16512) * 256 + t;
    int layer = e >> 16, rem = e & 65535;
    if (rem < 32768) {
        int k = rem >> 8, n = rem & 255;        // W1[k][n], K=128, N=256
        float v = gw1[layer * 32768 + rem];
        unsigned short h0 = f2bf(v);
        int o = layer * 32768 +
                ((((n >> 4) * 4 + (k >> 5)) * 64 + ((k >> 3) & 3) * 16 + (n & 15)) << 3) + (k & 7);
        w1h[o] = h0; w1l[o] = f2bf(v - bf2f(h0));
    } else {
        int rr = rem - 32768;
        int c = rr >> 7, n = rr & 127;          // W2[c][n], K=256, N=128
        float v = gw2[layer * 32768 + rr];
        unsigned short h0 = f2bf(v);
        int o = layer * 32768 +
                ((((n >> 4) * 8 + (c >> 5)) * 64 + ((c >> 3) & 3) * 16 + (n & 15)) << 3) + (c & 7);
        w2h[o] = h0; w2l[o] = f2bf(v - bf2f(h0));
    }
}

// =================== CSR build ===================
__global__ void k_count(const int* __restrict__ dst, int* __restrict__ counts) {
    int e = blockIdx.x * 256 + threadIdx.x;
    if (e < E_) atomicAdd(&counts[dst[e]], 1);
}

__global__ __launch_bounds__(1024) void k_scan(const int* __restrict__ counts,
                                               int* __restrict__ rowptr,
                                               int* __restrict__ woff) {
    __shared__ int lsums[1024];
    int t = threadIdx.x;
    int base = t * 32;
    int local[32];
    int s = 0;
    for (int i = 0; i < 32; i++) { local[i] = counts[base + i]; s += local[i]; }
    lsums[t] = s;
    __syncthreads();
    for (int off = 1; off < 1024; off <<= 1) {
        int v = lsums[t];
        int add = (t >= off) ? lsums[t - off] : 0;
        __syncthreads();
        lsums[t] = v + add;
        __syncthreads();
    }
    int excl = lsums[t] - s;
    for (int i = 0; i < 32; i++) {
        rowptr[base + i] = excl;
        woff[base + i]   = excl;
        excl += local[i];
    }
    if (t == 1023) rowptr[N_] = excl;
}

__global__ void k_fill(const int* __restrict__ src, const int* __restrict__ dst,
                       int* __restrict__ woff, int* __restrict__ col) {
    int e = blockIdx.x * 256 + threadIdx.x;
    if (e < E_) {
        int d = dst[e];
        int p = atomicAdd(&woff[d], 1);
        col[p] = src[e];
    }
}

// =================== fused GIN layer (r10 — verified) ===================
constexpr int LDH = 264;
constexpr int COLCAP = 1024;
__global__ __launch_bounds__(512) void k_gin(
    const float* __restrict__ hIn, const int* __restrict__ rowptr,
    const int* __restrict__ col,
    const unsigned short* __restrict__ w1h, const unsigned short* __restrict__ w1l,
    const unsigned short* __restrict__ w2h, const unsigned short* __restrict__ w2l,
    const float* __restrict__ b1, const float* __restrict__ b2,
    const float* __restrict__ gamma, const float* __restrict__ beta,
    int relu_out, float* __restrict__ hOut) {
    __shared__ int colS[COLCAP];
    __shared__ unsigned short bufH[32 * LDH];
    __shared__ unsigned short bufL[32 * LDH];
    int i = blockIdx.x;
    int xcd = i & 7;
    int slot = i >> 3;
    int g = (slot >> 4) * 8 + xcd;
    int tile = slot & 15;
    int rowBase = g * 512 + tile * 32;
    int t = threadIdx.x;
    int w = t >> 6, l = t & 63;
    int l15 = l & 15, quad = l >> 4;

    int ebase = rowptr[rowBase];
    int ecnt  = rowptr[rowBase + 32] - ebase;
    bool inLds = (ecnt <= COLCAP);
    if (inLds)
        for (int j = t; j < ecnt; j += 512) colS[j] = col[ebase + j];
    __syncthreads();

    #pragma unroll
    for (int jj = 0; jj < 4; jj++) {
        int row = w * 4 + jj;
        int node = rowBase + row;
        int beg = rowptr[node], end = rowptr[node + 1];
        float a0 = hIn[(size_t)node * D_ + l];
        float a1 = hIn[(size_t)node * D_ + l + 64];
        int e = beg;
        for (; e + 8 <= end; e += 8) {
            int c[8];
            #pragma unroll
            for (int u = 0; u < 8; u++)
                c[u] = inLds ? colS[e - ebase + u] : col[e + u];
            float p[8], q[8];
            #pragma unroll
            for (int u = 0; u < 8; u++) {
                p[u] = hIn[(size_t)c[u] * D_ + l];
                q[u] = hIn[(size_t)c[u] * D_ + l + 64];
            }
            #pragma unroll
            for (int u = 0; u < 8; u++) { a0 += p[u]; a1 += q[u]; }
        }
        for (; e < end; e++) {
            int c = inLds ? colS[e - ebase] : col[e];
            a0 += hIn[(size_t)c * D_ + l];
            a1 += hIn[(size_t)c * D_ + l + 64];
        }
        unsigned short h0 = f2bf(a0);
        bufH[row * LDH + l] = h0;
        bufL[row * LDH + l] = f2bf(a0 - bf2f(h0));
        unsigned short h1 = f2bf(a1);
        bufH[row * LDH + l + 64] = h1;
        bufL[row * LDH + l + 64] = f2bf(a1 - bf2f(h1));
    }
    __syncthreads();

    f32x4_t acc[2][2];
    #pragma unroll
    for (int nt = 0; nt < 2; nt++) {
        float bb = b1[w * 32 + nt * 16 + l15];
        acc[0][nt] = (f32x4_t){bb, bb, bb, bb};
        acc[1][nt] = (f32x4_t){bb, bb, bb, bb};
    }
    #pragma unroll
    for (int kk = 0; kk < 4; kk++) {
        bf16x8_t ah[2], al[2];
        #pragma unroll
        for (int mt = 0; mt < 2; mt++) {
            int addr = (mt * 16 + l15) * LDH + kk * 32 + quad * 8;
            ah[mt] = *(const bf16x8_t*)&bufH[addr];
            al[mt] = *(const bf16x8_t*)&bufL[addr];
        }
        #pragma unroll
        for (int nt = 0; nt < 2; nt++) {
            int n16 = w * 2 + nt;
            int ga = (((n16 * 4 + kk) * 64 + l) << 3);
            bf16x8_t bh = *(const bf16x8_t*)&w1h[ga];
            bf16x8_t bl = *(const bf16x8_t*)&w1l[ga];
            acc[0][nt] = mfma3(ah[0], al[0], bh, bl, acc[0][nt]);
            acc[1][nt] = mfma3(ah[1], al[1], bh, bl, acc[1][nt]);
        }
    }
    __syncthreads();

    #pragma unroll
    for (int mt = 0; mt < 2; mt++)
        #pragma unroll
        for (int nt = 0; nt < 2; nt++) {
            int colL = w * 32 + nt * 16 + l15;
            #pragma unroll
            for (int r = 0; r < 4; r++) {
                int row = mt * 16 + quad * 4 + r;
                float v = fmaxf(acc[mt][nt][r], 0.f);
                unsigned short h0 = f2bf(v);
                bufH[row * LDH + colL] = h0;
                bufL[row * LDH + colL] = f2bf(v - bf2f(h0));
            }
        }
    __syncthreads();

    f32x4_t acc2[2];
    {
        float bb = b2[w * 16 + l15];
        acc2[0] = (f32x4_t){bb, bb, bb, bb};
        acc2[1] = (f32x4_t){bb, bb, bb, bb};
    }
    #pragma unroll
    for (int kkG = 0; kkG < 8; kkG++) {
        bf16x8_t ah[2], al[2];
        #pragma unroll
        for (int mt = 0; mt < 2; mt++) {
            int addr = (mt * 16 + l15) * LDH + kkG * 32 + quad * 8;
            ah[mt] = *(const bf16x8_t*)&bufH[addr];
            al[mt] = *(const bf16x8_t*)&bufL[addr];
        }
        int ga = (((w * 8 + kkG) * 64 + l) << 3);
        bf16x8_t bh = *(const bf16x8_t*)&w2h[ga];
        bf16x8_t bl = *(const bf16x8_t*)&w2l[ga];
        acc2[0] = mfma3(ah[0], al[0], bh, bl, acc2[0]);
        acc2[1] = mfma3(ah[1], al[1], bh, bl, acc2[1]);
    }
    {
        int colC = w * 16 + l15;
        float gm = BN_SCALE_ * gamma[colC];
        float be = beta[colC];
        #pragma unroll
        for (int mt = 0; mt < 2; mt++)
            #pragma unroll
            for (int r = 0; r < 4; r++) {
                int row = mt * 16 + quad * 4 + r;
                float v = fmaf(acc2[mt][r], gm, be);
                if (relu_out) v = fmaxf(v, 0.f);
                hOut[(size_t)(rowBase + row) * 128 + colC] = v;
            }
    }
}

// =================== partitioner + cf1 fused (512 blocks) + tinit (blocks 512..1103) ===================
__global__ __launch_bounds__(256) void k_partcf_tinit(
    const float* __restrict__ h,
    const float* __restrict__ W1, const float* __restrict__ b1,
    const float* __restrict__ W2, const float* __restrict__ b2,
    float* __restrict__ pacc, float* __restrict__ pss, float* __restrict__ prs,
    float* __restrict__ qbuf, float* __restrict__ kbuf,
    float* __restrict__ vbuf, float* __restrict__ catbuf,
    float* __restrict__ g1h, float* __restrict__ z1, float* __restrict__ z2,
    const float* __restrict__ gb1, const float* __restrict__ cb1,
    const float* __restrict__ cb2) {
    __shared__ float zt[64 * 128];
    __shared__ float ht[64 * 52];
    __shared__ float lt[64 * 5];
    __shared__ float red[128 * 6];
    __shared__ float ssred[10];
    int t = threadIdx.x;
    if (blockIdx.x >= 512) {
        int i = (blockIdx.x - 512) * 256 + t;
        if (i < 8192) { qbuf[i] = 0.f; return; }
        if (i < 49152) { kbuf[i - 8192] = 0.f; return; }
        if (i < 90112) { vbuf[i - 49152] = 0.f; return; }
        if (i < 98304) { int j = i - 90112; catbuf[(j >> 7) * 256 + 128 + (j & 127)] = 0.f; return; }
        if (i < 102400) { int j = i - 98304; g1h[j] = gb1[j & 63]; return; }
        if (i < 135168) { int j = i - 102400; z1[j] = cb1[j & 511]; return; }
        if (i < 151552) { int j = i - 135168; z2[j] = cb2[j & 255]; return; }
        return;
    }
    int blk = blockIdx.x;
    int base = blk * 64;
    #pragma unroll
    for (int i = 0; i < 32; i++) { int idx = t + i * 256; zt[idx] = h[(size_t)base * D_ + idx]; }
    __syncthreads();
    int tx = t & 63, ty = t >> 6, r0 = ty * 16;
    if (tx < NHID_) {
        float acc[16];
        float bb = b1[tx];
        #pragma unroll
        for (int r = 0; r < 16; r++) acc[r] = bb;
        for (int k = 0; k < 128; k++) {
            float w = W1[k * NHID_ + tx];
            #pragma unroll
            for (int r = 0; r < 16; r++) acc[r] = fmaf(zt[(r0 + r) * 128 + k], w, acc[r]);
        }
        #pragma unroll
        for (int r = 0; r < 16; r++) ht[(r0 + r) * 52 + tx] = fmaxf(acc[r], 0.f);
    }
    __syncthreads();
    if (tx < K_) {
        float acc[16];
        float bb = b2[tx];
        #pragma unroll
        for (int r = 0; r < 16; r++) acc[r] = bb;
        for (int c = 0; c < NHID_; c++) {
            float w = W2[c * K_ + tx];
            #pragma unroll
            for (int r = 0; r < 16; r++) acc[r] = fmaf(ht[(r0 + r) * 52 + c], w, acc[r]);
        }
        #pragma unroll
        for (int r = 0; r < 16; r++) lt[(r0 + r) * 5 + tx] = acc[r];
    }
    __syncthreads();
    if (t < 64) {
        float l0 = lt[t*5], l1 = lt[t*5+1], l2 = lt[t*5+2], l3 = lt[t*5+3], l4 = lt[t*5+4];
        float m = fmaxf(fmaxf(fmaxf(l0, l1), fmaxf(l2, l3)), l4);
        float e0 = expf(l0 - m), e1 = expf(l1 - m), e2 = expf(l2 - m),
              e3 = expf(l3 - m), e4 = expf(l4 - m);
        float inv = 1.0f / (e0 + e1 + e2 + e3 + e4);
        lt[t*5]   = e0*inv; lt[t*5+1] = e1*inv; lt[t*5+2] = e2*inv;
        lt[t*5+3] = e3*inv; lt[t*5+4] = e4*inv;
    }
    __syncthreads();
    int d = t & 127, grp = t >> 7;
    float acc[5] = {0,0,0,0,0}, ssum[5] = {0,0,0,0,0}, rs = 0;
    #pragma unroll 4
    for (int i = 0; i < 32; i++) {
        int nl = grp * 32 + i;
        float hv = zt[nl * 128 + d];
        rs += hv;
        #pragma unroll
        for (int k = 0; k < 5; k++) {
            float sv = lt[nl * 5 + k];
            acc[k] = fmaf(sv, hv, acc[k]);
            ssum[k] += sv;
        }
    }
    if (grp == 1) {
        #pragma unroll
        for (int k = 0; k < 5; k++) red[d * 6 + k] = acc[k];
        red[d * 6 + 5] = rs;
    }
    if (d == 0) {
        #pragma unroll
        for (int k = 0; k < 5; k++) ssred[grp * 5 + k] = ssum[k];
    }
    __syncthreads();
    if (grp == 0) {
        #pragma unroll
        for (int k = 0; k < 5; k++) {
            acc[k] += red[d * 6 + k];
            pacc[((size_t)blk * 5 + k) * 128 + d] = acc[k];
        }
        rs += red[d * 6 + 5];
        prs[blk * 128 + d] = rs;
        if (d < 5) pss[blk * 5 + d] = ssred[d] + ssred[5 + d];
    }
}

// =================== cf stage 2 + VQ fused (320 blocks, one per (g,k)) ===================
__global__ __launch_bounds__(256) void k_cf2vq(
    const float* __restrict__ pacc, const float* __restrict__ pss,
    const float* __restrict__ prs, const float* __restrict__ cb,
    float* __restrict__ residue, float* __restrict__ catbuf,
    float* __restrict__ zq) {
    __shared__ float row[128];
    __shared__ float bd[256];
    __shared__ int bi[256];
    int r = blockIdx.x;           // g*5 + k
    int g = r / 5, k = r - g * 5;
    int t = threadIdx.x;
    if (t < 128) {
        float acc = 0, ss = 0;
        for (int ch = 0; ch < 8; ch++) {
            int blk = g * 8 + ch;
            acc += pacc[((size_t)blk * 5 + k) * 128 + t];
            ss  += pss[blk * 5 + k];
        }
        row[t] = acc / (ss + EPS_);
        if (k == 0) {
            float rs = 0;
            for (int ch = 0; ch < 8; ch++) rs += prs[(g * 8 + ch) * 128 + t];
            float rm = rs * (1.0f / 512.0f);
            residue[g * 128 + t] = rm;
            catbuf[g * 256 + t]  = rm;
        }
    }
    __syncthreads();
    float best = 1e30f; int bidx = 0;
    const float4* r4p = (const float4*)row;
    for (int j = t; j < CB_; j += 256) {
        const float4* cbr = (const float4*)(cb + j * 128);
        float d2 = 0;
        #pragma unroll 8
        for (int q = 0; q < 32; q++) {
            float4 c4 = cbr[q], r4 = r4p[q];
            float dx = r4.x - c4.x, dy = r4.y - c4.y;
            float dz = r4.z - c4.z, dw = r4.w - c4.w;
            d2 = fmaf(dx, dx, d2); d2 = fmaf(dy, dy, d2);
            d2 = fmaf(dz, dz, d2); d2 = fmaf(dw, dw, d2);
        }
        if (d2 < best || (d2 == best && j < bidx)) { best = d2; bidx = j; }
    }
    bd[t] = best; bi[t] = bidx;
    __syncthreads();
    for (int s = 128; s > 0; s >>= 1) {
        if (t < s) {
            if (bd[t + s] < bd[t] || (bd[t + s] == bd[t] && bi[t + s] < bi[t])) {
                bd[t] = bd[t + s]; bi[t] = bi[t + s];
            }
        }
        __syncthreads();
    }
    int idx = bi[0];
    if (t < 128) zq[r * 128 + t] = cb[idx * 128 + t];
}

// =================== high-parallelism small GEMM core (atomic split-K) ===================
__device__ __forceinline__ void gemm_tile_atomic(
    const float* __restrict__ A, int lda, int kc,
    const float* __restrict__ W, int ldw,
    float* __restrict__ C, int ldc, int coff, int actA,
    float* aT, float* wT) {
    int t = threadIdx.x;
    for (int i = t; i < 1024; i += 256) {
        int r = i >> 4, c4 = (i & 15) << 2;
        float4 av = *(const float4*)&A[(size_t)r * lda + kc + c4];
        if (actA) {
            av.x = fmaxf(av.x, 0.f); av.y = fmaxf(av.y, 0.f);
            av.z = fmaxf(av.z, 0.f); av.w = fmaxf(av.w, 0.f);
        }
        *(float4*)&aT[r * 68 + c4] = av;
        *(float4*)&wT[r * 68 + c4] = *(const float4*)&W[(size_t)(kc + r) * ldw + coff + c4];
    }
    __syncthreads();
    int tx = t & 15, ty = t >> 4;
    float acc[4][4] = {};
    #pragma unroll 4
    for (int k = 0; k < 64; k += 4) {
        float w[4][4];
        #pragma unroll
        for (int kk = 0; kk < 4; kk++)
            #pragma unroll
            for (int j = 0; j < 4; j++)
                w[kk][j] = wT[(k + kk) * 68 + tx + j * 16];
        #pragma unroll
        for (int r = 0; r < 4; r++) {
            float4 av = *(const float4*)&aT[(ty * 4 + r) * 68 + k];
            #pragma unroll
            for (int j = 0; j < 4; j++) {
                acc[r][j] = fmaf(av.x, w[0][j], acc[r][j]);
                acc[r][j] = fmaf(av.y, w[1][j], acc[r][j]);
                acc[r][j] = fmaf(av.z, w[2][j], acc[r][j]);
                acc[r][j] = fmaf(av.w, w[3][j], acc[r][j]);
            }
        }
    }
    #pragma unroll
    for (int r = 0; r < 4; r++)
        #pragma unroll
        for (int j = 0; j < 4; j++)
            atomicAdd(&C[(size_t)(ty * 4 + r) * ldc + coff + tx + j * 16], acc[r][j]);
}

__global__ __launch_bounds__(256) void k_gemm_gen(
    const float* __restrict__ A, int lda,
    const float* __restrict__ W, int ldw,
    float* __restrict__ C, int ldc, int actA) {
    __shared__ float aT[64 * 68];
    __shared__ float wT[64 * 68];
    gemm_tile_atomic(A, lda, blockIdx.y * 64, W, ldw, C, ldc, blockIdx.x * 64, actA, aT, wT);
}

__global__ __launch_bounds__(256) void k_gemm_qkv(
    const float* __restrict__ residue, const float* __restrict__ zq,
    const float* __restrict__ Wq, const float* __restrict__ Wk, const float* __restrict__ Wv,
    float* __restrict__ qbuf, float* __restrict__ kbuf, float* __restrict__ vbuf) {
    __shared__ float aT[64 * 68];
    __shared__ float wT[64 * 68];
    int z = blockIdx.z;
    const float* A; const float* W; float* C;
    if (z == 0)      { A = residue;                W = Wq; C = qbuf; }
    else if (z < 6)  { A = zq + (z - 1) * 64 * 128; W = Wk; C = kbuf + (z - 1) * 64 * 128; }
    else             { A = zq + (z - 6) * 64 * 128; W = Wv; C = vbuf + (z - 6) * 64 * 128; }
    gemm_tile_atomic(A, 128, blockIdx.y * 64, W, 128, C, 128, blockIdx.x * 64, 0, aT, wT);
}

// =================== attention ===================
__global__ __launch_bounds__(128) void k_attn(
    const float* __restrict__ qbuf, const float* __restrict__ kbuf,
    const float* __restrict__ vbuf, float* __restrict__ attbuf) {
    __shared__ float q[128], kk5[640], vv5[640], aw[20];
    int b = blockIdx.x, t = threadIdx.x;
    q[t] = qbuf[b * 128 + t];
    #pragma unroll
    for (int j = 0; j < 5; j++) {
        kk5[j * 128 + t] = kbuf[(b * 5 + j) * 128 + t];
        vv5[j * 128 + t] = vbuf[(b * 5 + j) * 128 + t];
    }
    __syncthreads();
    if (t < 20) {
        int hh = t / 5, j = t % 5;
        float s = 0;
        #pragma unroll
        for (int d = 0; d < 32; d++) s = fmaf(q[hh * 32 + d], kk5[j * 128 + hh * 32 + d], s);
        aw[t] = s * 0.17677669529663687f;
    }
    __syncthreads();
    if (t < 4) {
        float m = -1e30f;
        for (int j = 0; j < 5; j++) m = fmaxf(m, aw[t * 5 + j]);
        float e[5], sum = 0;
        for (int j = 0; j < 5; j++) { e[j] = expf(aw[t * 5 + j] - m); sum += e[j]; }
        for (int j = 0; j < 5; j++) aw[t * 5 + j] = e[j] / sum;
    }
    __syncthreads();
    int hh = t >> 5;
    float a = 0;
    #pragma unroll
    for (int j = 0; j < 5; j++) a = fmaf(aw[hh * 5 + j], vv5[j * 128 + t], a);
    attbuf[b * 128 + t] = a;
}

// =================== gate2 + sigmoid + fuse (relu on g1h read) ===================
__global__ __launch_bounds__(256) void k_fuse(
    const float* __restrict__ g1h, const float* __restrict__ gW2,
    const float* __restrict__ gb2, const float* __restrict__ residue,
    const float* __restrict__ catbuf, float* __restrict__ fusedbuf) {
    __shared__ float aT[64 * 68];
    __shared__ float wT[64 * 68];
    int t = threadIdx.x;
    int coff = blockIdx.x * 64;
    for (int i = t; i < 1024; i += 256) {
        int r = i >> 4, c4 = (i & 15) << 2;
        float4 av = *(const float4*)&g1h[r * 64 + c4];
        av.x = fmaxf(av.x, 0.f); av.y = fmaxf(av.y, 0.f);
        av.z = fmaxf(av.z, 0.f); av.w = fmaxf(av.w, 0.f);
        *(float4*)&aT[r * 68 + c4] = av;
        *(float4*)&wT[r * 68 + c4] = *(const float4*)&gW2[r * 128 + coff + c4];
    }
    __syncthreads();
    int tx = t & 15, ty = t >> 4;
    float acc[4][4] = {};
    #pragma unroll 4
    for (int k = 0; k < 64; k += 4) {
        float w[4][4];
        #pragma unroll
        for (int kk = 0; kk < 4; kk++)
            #pragma unroll
            for (int j = 0; j < 4; j++)
                w[kk][j] = wT[(k + kk) * 68 + tx + j * 16];
        #pragma unroll
        for (int r = 0; r < 4; r++) {
            float4 av = *(const float4*)&aT[(ty * 4 + r) * 68 + k];
            #pragma unroll
            for (int j = 0; j < 4; j++) {
                acc[r][j] = fmaf(av.x, w[0][j], acc[r][j]);
                acc[r][j] = fmaf(av.y, w[1][j], acc[r][j]);
                acc[r][j] = fmaf(av.z, w[2][j], acc[r][j]);
                acc[r][j] = fmaf(av.w, w[3][j], acc[r][j]);
            }
        }
    }
    #pragma unroll
    for (int r = 0; r < 4; r++)
        #pragma unroll
        for (int j = 0; j < 4; j++) {
            int col = coff + tx + j * 16;
            int row = ty * 4 + r;
            float gv = 1.f / (1.f + expf(-(acc[r][j] + gb2[col])));
            float rv = residue[row * 128 + col];
            float av = catbuf[row * 256 + 128 + col];
            fusedbuf[row * 128 + col] = gv * rv + (1.f - gv) * av;
        }
}

// =================== cls3 (relu on z2 read) ===================
__global__ __launch_bounds__(256) void k_cls3(
    const float* __restrict__ z2, const float* __restrict__ cW3,
    const float* __restrict__ cb3, float* __restrict__ out) {
    __shared__ float red[8];
    int row = blockIdx.x, t = threadIdx.x;
    float zv = fmaxf(z2[row * 256 + t], 0.f);
    float a0 = zv * cW3[t * 2];
    float a1 = zv * cW3[t * 2 + 1];
    #pragma unroll
    for (int off = 32; off > 0; off >>= 1) {
        a0 += __shfl_down(a0, off, 64);
        a1 += __shfl_down(a1, off, 64);
    }
    int wv = t >> 6;
    if ((t & 63) == 0) { red[wv * 2] = a0; red[wv * 2 + 1] = a1; }
    __syncthreads();
    if (t < 2) {
        float s = cb3[t] + red[t] + red[2 + t] + red[4 + t] + red[6 + t];
        out[row * 2 + t] = s;
    }
}

// =================== launch ===================
extern "C" void kernel_launch(void* const* d_in, const int* in_sizes, int n_in,
                              void* d_out, int out_size, void* d_ws, size_t ws_size,
                              hipStream_t stream) {
    const int*   x          = (const int*)d_in[0];
    const int*   edge_index = (const int*)d_in[1];
    const float* emb      = (const float*)d_in[3];
    const float* gin_W1   = (const float*)d_in[4];
    const float* gin_b1   = (const float*)d_in[5];
    const float* gin_W2   = (const float*)d_in[6];
    const float* gin_b2   = (const float*)d_in[7];
    const float* bn_gamma = (const float*)d_in[8];
    const float* bn_beta  = (const float*)d_in[9];
    const float* part_W1  = (const float*)d_in[10];
    const float* part_b1  = (const float*)d_in[11];
    const float* part_W2  = (const float*)d_in[12];
    const float* part_b2  = (const float*)d_in[13];
    const float* Wq       = (const float*)d_in[14];
    const float* Wk       = (const float*)d_in[15];
    const float* Wv       = (const float*)d_in[16];
    const float* Wo       = (const float*)d_in[17];
    const float* gate_W1  = (const float*)d_in[18];
    const float* gate_b1  = (const float*)d_in[19];
    const float* gate_W2  = (const float*)d_in[20];
    const float* gate_b2  = (const float*)d_in[21];
    const float* codebook = (const float*)d_in[22];
    const float* cls_W1   = (const float*)d_in[23];
    const float* cls_b1   = (const float*)d_in[24];
    const float* cls_W2   = (const float*)d_in[25];
    const float* cls_b2   = (const float*)d_in[26];
    const float* cls_W3   = (const float*)d_in[27];
    const float* cls_b3   = (const float*)d_in[28];

    const int* srcp = edge_index;
    const int* dstp = edge_index + E_;

    // ---- workspace carve ----
    char* w = (char*)d_ws;
    float* hA = (float*)w;  w += (size_t)N_ * D_ * 4;   // embed + L1 out
    float* hB = (float*)w;  w += (size_t)N_ * D_ * 4;   // L0/L2 out (final features)
    int* counts = (int*)w;  w += (size_t)N_ * 4;
    int* rowptr = (int*)w;  w += (size_t)(N_ + 4) * 4;
    int* woff   = (int*)w;  w += (size_t)N_ * 4;
    int* col    = (int*)w;  w += (size_t)E_ * 4;
    unsigned short* w1h = (unsigned short*)w;  w += (size_t)3 * 32768 * 2;
    unsigned short* w1l = (unsigned short*)w;  w += (size_t)3 * 32768 * 2;
    unsigned short* w2h = (unsigned short*)w;  w += (size_t)3 * 32768 * 2;
    unsigned short* w2l = (unsigned short*)w;  w += (size_t)3 * 32768 * 2;

    // tail buffers live inside hA (dead after GIN L2 reads it)
    char* tz = (char*)hA;
    float* pacc     = (float*)tz;  tz += (size_t)512 * 5 * 128 * 4;
    float* pss      = (float*)tz;  tz += (size_t)512 * 5 * 4;
    float* prs      = (float*)tz;  tz += (size_t)512 * 128 * 4;
    float* zqb      = (float*)tz;  tz += (size_t)B_ * 5 * D_ * 4;
    float* residue  = (float*)tz;  tz += (size_t)B_ * D_ * 4;
    float* catbuf   = (float*)tz;  tz += (size_t)B_ * 2 * D_ * 4;
    float* qbuf     = (float*)tz;  tz += (size_t)B_ * D_ * 4;
    float* kbuf     = (float*)tz;  tz += (size_t)B_ * 5 * D_ * 4;
    float* vbuf     = (float*)tz;  tz += (size_t)B_ * 5 * D_ * 4;
    float* attbuf   = (float*)tz;  tz += (size_t)B_ * D_ * 4;
    float* g1h      = (float*)tz;  tz += (size_t)B_ * 64 * 4;
    float* fusedbuf = (float*)tz;  tz += (size_t)B_ * D_ * 4;
    float* z1       = (float*)tz;  tz += (size_t)B_ * 512 * 4;
    float* z2       = (float*)tz;  tz += (size_t)B_ * 256 * 4;

    // ---- prep (zero+embed+wprep) + CSR ----
    k_prep<<<17280, 256, 0, stream>>>(x, emb, hA, counts, gin_W1, gin_W2, w1h, w1l, w2h, w2l);
    k_count<<<E_ / 256, 256, 0, stream>>>(dstp, counts);
    k_scan <<<1, 1024, 0, stream>>>(counts, rowptr, woff);
    k_fill <<<E_ / 256, 256, 0, stream>>>(srcp, dstp, woff, col);

    // ---- GIN layers (fused agg+MLP, ping-pong hA/hB; final in hB) ----
    const float* hin[3] = {hA, hB, hA};
    float*       hout[3] = {hB, hA, hB};
    for (int l = 0; l < 3; l++) {
        k_gin<<<1024, 512, 0, stream>>>(
            hin[l], rowptr, col,
            w1h + (size_t)l * 32768, w1l + (size_t)l * 32768,
            w2h + (size_t)l * 32768, w2l + (size_t)l * 32768,
            gin_b1 + (size_t)l * 256, gin_b2 + (size_t)l * 128,
            bn_gamma + (size_t)l * 128, bn_beta + (size_t)l * 128,
            (l < 2) ? 1 : 0, hout[l]);
    }

    // ---- tail (r10 structure; partitioner+cf1+tinit fused) ----
    k_partcf_tinit<<<512 + 592, 256, 0, stream>>>(hB, part_W1, part_b1, part_W2, part_b2,
                                                  pacc, pss, prs,
                                                  qbuf, kbuf, vbuf, catbuf, g1h, z1, z2,
                                                  gate_b1, cls_b1, cls_b2);
    k_cf2vq<<<320, 256, 0, stream>>>(pacc, pss, prs, codebook, residue, catbuf, zqb);
    k_gemm_qkv<<<dim3(2, 2, 11), 256, 0, stream>>>(residue, zqb, Wq, Wk, Wv, qbuf, kbuf, vbuf);
    k_attn<<<B_, 128, 0, stream>>>(qbuf, kbuf, vbuf, attbuf);
    k_gemm_gen<<<dim3(2, 2), 256, 0, stream>>>(attbuf, 128, Wo, 128, catbuf + 128, 256, 0);
    k_gemm_gen<<<dim3(1, 4), 256, 0, stream>>>(catbuf, 256, gate_W1, 64, g1h, 64, 0);
    k_fuse<<<2, 256, 0, stream>>>(g1h, gate_W2, gate_b2, residue, catbuf, fusedbuf);
    k_gemm_gen<<<dim3(8, 2), 256, 0, stream>>>(fusedbuf, 128, cls_W1, 512, z1, 512, 0);
    k_gemm_gen<<<dim3(4, 8), 256, 0, stream>>>(z1, 512, cls_W2, 256, z2, 256, 1);
    k_cls3<<<B_, 256, 0, stream>>>(z2, cls_W3, cls_b3, (float*)d_out);
}